// Round 7
// baseline (1372.443 us; speedup 1.0000x reference)
//
#include <hip/hip_runtime.h>
#include <hip/hip_bf16.h>
#include <cstdint>
#include <cstddef>

// ---------------- problem constants ----------------
#define BB 8
#define NN 8192
#define MM 1024
#define SS 32
#define PTOT (BB*MM*SS)          // 262144
// threshold must match f32(0.2*0.2 computed in double) — NOT 0.2f*0.2f
__device__ __constant__ float kR2 = 0.039999999105930328f;

// ---------------- stats layout (float offsets in ws) ----------------
#define ST_SUM0L 0
#define ST_SQ0L  64
#define ST_SUM0F 128
#define ST_SQ0F  192
#define ST_SUM1  256
#define ST_SQ1   320
#define ST_SUM2  384
#define ST_SQ2   512
#define P_AL     640
#define P_BL     704
#define P_AF     768
#define P_BF     832
#define P_A1     896
#define P_B1     960
#define P_A2     1024
#define P_B2     1152
#define STATS_ZERO_BYTES (640*4)

// ws byte offsets
#define OFF_FPS   0u
#define OFF_STATS 32768u
#define OFF_X0    40960u
#define OFF_Z1    12623872u      // x0 ends at 40960 + 262144*48 = 12623872

typedef float v2f __attribute__((ext_vector_type(2)));
typedef unsigned long long ull;

// u64-key max over DPP (rocPRIM wave64 ctrl sequence, validated R3-R5).
// Both halves use identical ctrl/masks -> pair comes from the same lane;
// masked/out-of-bounds lanes keep own value (max(v,v)=v harmless).
#define DPP_KMAX(k, ctrl, rm, bm) {                                        \
  const unsigned _lo = (unsigned)(k), _hi = (unsigned)((k) >> 32);         \
  const unsigned _nl = (unsigned)__builtin_amdgcn_update_dpp(              \
      (int)_lo, (int)_lo, ctrl, rm, bm, false);                            \
  const unsigned _nh = (unsigned)__builtin_amdgcn_update_dpp(              \
      (int)_hi, (int)_hi, ctrl, rm, bm, false);                            \
  const ull _o = ((ull)_nh << 32) | _nl;                                   \
  k = (_o > (k)) ? _o : (k); }

// ==================================================================
// 1) FPS v10: R3 geometry (512 thr / 8 waves / 16 pts per thread,
//    2 waves/SIMD) + R5's u64-key single-reduce. Rationale (R4/R5
//    post-mortem): per-SIMD issue work is ~wave-count-invariant
//    (dist + key tree fixed per SIMD; DPP adds ~60cyc per extra
//    wave), while the ~700cyc serial chain (LDS broadcast, key
//    write/read, DPP deps, barrier) ran fully exposed at 1 wave/SIMD
//    (R5: 736 stall cyc/iter). A second wave per SIMD fills it.
//    R4's "fewer waves wins" was measured under the OLD expensive
//    per-wave reduce (~250 inst/wave); u64 path is ~70.
//    key = (f32bits(T)<<32) | ~idx: max key == max distance, lowest
//    index on ties (np.argmax semantics, proven R0-R5 chain).
//    Distance op order unchanged (contract off) -> bit-identical d.
// ==================================================================
__global__ __launch_bounds__(512, 2) void fps_kernel(const float* __restrict__ center,
                                                     int* __restrict__ fps_idx) {
  const int b = blockIdx.x;
  const int t = threadIdx.x;               // 0..511
  const int lane = t & 63, wid = t >> 6;   // 8 waves
  const float* cb = center + (size_t)b * NN * 3;
  __shared__ __align__(16) float4 sc[NN];            // 128 KB centroid table
  __shared__ ull s_wkey[2][8];
  v2f X[8], Y[8], Z[8], T[8];
#pragma unroll
  for (int j = 0; j < 8; ++j) {
    const int p0 = ((2 * j) << 9) | t;
    const int p1 = ((2 * j + 1) << 9) | t;
    const float x0 = cb[p0 * 3 + 0], y0 = cb[p0 * 3 + 1], z0 = cb[p0 * 3 + 2];
    const float x1 = cb[p1 * 3 + 0], y1 = cb[p1 * 3 + 1], z1 = cb[p1 * 3 + 2];
    sc[p0] = make_float4(x0, y0, z0, 0.f);
    sc[p1] = make_float4(x1, y1, z1, 0.f);
    X[j] = (v2f){x0, x1}; Y[j] = (v2f){y0, y1}; Z[j] = (v2f){z0, z1};
    T[j] = (v2f){1e10f, 1e10f};
    // pin: asm-defined values cannot be rematerialized from memory
    asm volatile("" : "+v"(X[j]), "+v"(Y[j]), "+v"(Z[j]));
  }
  __syncthreads();
  int far = 0;
  for (int i = 0; i < MM; ++i) {
    if (t == 0) fps_idx[(b << 10) + i] = far;
    // centroid: uniform-address LDS broadcast read
    const float4 c = sc[__builtin_amdgcn_readfirstlane(far)];
    const v2f cx2 = (v2f){c.x, c.x};
    const v2f cy2 = (v2f){c.y, c.y};
    const v2f cz2 = (v2f){c.z, c.z};
    {
#pragma clang fp contract(off)
#pragma unroll
      for (int j = 0; j < 8; ++j) {
        const v2f dx = X[j] - cx2;
        const v2f dy = Y[j] - cy2;
        const v2f dz = Z[j] - cz2;
        v2f d = dx * dx;
        d = d + dy * dy;
        d = d + dz * dz;
        T[j] = __builtin_elementwise_min(T[j], d);
      }
    }
    // ---- per-thread u64 key tree (max dist, lowest idx on ties) ----
    ull K[8];
#pragma unroll
    for (int j = 0; j < 8; ++j) {
      const unsigned hx = __float_as_uint(T[j].x);
      const unsigned hy = __float_as_uint(T[j].y);
      const bool ygt = hy > hx;            // tie -> keep x (lower idx)
      const unsigned h = ygt ? hy : hx;
      const unsigned l = ygt ? ~(unsigned)(((2 * j + 1) << 9) | t)
                             : ~(unsigned)(((2 * j) << 9) | t);
      K[j] = ((ull)h << 32) | l;
    }
#pragma unroll
    for (int s = 4; s >= 1; s >>= 1) {
#pragma unroll
      for (int j = 0; j < s; ++j) {
        const ull o = K[j + s];
        if (o > K[j]) K[j] = o;
      }
    }
    ull key = K[0];
    // ---- wave u64 max via DPP (lane 63 ends with the full reduce) ----
    DPP_KMAX(key, 0x111, 0xf, 0xf)
    DPP_KMAX(key, 0x112, 0xf, 0xf)
    DPP_KMAX(key, 0x114, 0xf, 0xe)
    DPP_KMAX(key, 0x118, 0xf, 0xc)
    DPP_KMAX(key, 0x142, 0xa, 0xf)
    DPP_KMAX(key, 0x143, 0xc, 0xf)
    if (lane == 63) s_wkey[i & 1][wid] = key;
    __syncthreads();
    const ull* sk = s_wkey[i & 1];
    const ull k0 = sk[0], k1 = sk[1], k2 = sk[2], k3 = sk[3];
    const ull k4 = sk[4], k5 = sk[5], k6 = sk[6], k7 = sk[7];
    const ull h0 = (k1 > k0) ? k1 : k0;
    const ull h1 = (k3 > k2) ? k3 : k2;
    const ull h2 = (k5 > k4) ? k5 : k4;
    const ull h3 = (k7 > k6) ? k7 : k6;
    const ull g0 = (h1 > h0) ? h1 : h0;
    const ull g1 = (h3 > h2) ? h3 : h2;
    const ull best = (g1 > g0) ? g1 : g0;
    far = (int)(~(unsigned)best);
  }
}

// ==================================================================
// 2) Ball query (first 32 smallest in-radius indices) + gather + concat
//    one wave per (b,m); also writes new_center/new_normal outputs
// ==================================================================
__global__ __launch_bounds__(256) void ball_gather_kernel(
    const float* __restrict__ center, const float* __restrict__ normal,
    const float* __restrict__ feature, const int* __restrict__ fps_idx,
    float* __restrict__ x0, float* __restrict__ out) {
  const int lane = threadIdx.x & 63;
  const int wq = (int)((blockIdx.x * blockDim.x + threadIdx.x) >> 6); // 0..8191
  const int b = wq >> 10, m = wq & 1023;
  const float* cb = center  + (size_t)b * NN * 3;
  const float* nb = normal  + (size_t)b * NN * 3;
  const float* fb = feature + (size_t)b * 6 * NN;
  const int pstar = fps_idx[(b << 10) + m];
  const float qx = cb[pstar * 3 + 0], qy = cb[pstar * 3 + 1], qz = cb[pstar * 3 + 2];
  if (lane < 3) {
    out[b * 3072 + lane * 1024 + m]         = cb[pstar * 3 + lane];   // new_center^T
    out[24576 + b * 3072 + lane * 1024 + m] = nb[pstar * 3 + lane];   // new_normal^T
  }
  const size_t pos_base = (size_t)((b << 10) + m) * SS;
  int total = 0;
  int first_p = -1;
  const float r2 = kR2;
  for (int base = 0; base < NN && total < SS; base += 64) {
    const int p = base + lane;
    const float ppx = cb[p * 3], ppy = cb[p * 3 + 1], ppz = cb[p * 3 + 2];
    const float dx = ppx - qx, dy = ppy - qy, dz = ppz - qz;
    float d2;
    {
#pragma clang fp contract(off)
      d2 = dx * dx;
      d2 = d2 + dy * dy;
      d2 = d2 + dz * dz;
    }
    const bool hit = d2 < r2;
    const unsigned long long msk = __ballot(hit);
    if (first_p < 0 && msk) first_p = base + (int)__builtin_ctzll(msk);
    const int rank = (int)__popcll(msk & ((1ull << lane) - 1ull));
    const int slot = total + rank;
    if (hit && slot < SS) {
      float4 v0, v1, v2;
      v0.x = dx; v0.y = dy; v0.z = dz;             // group_center - new_center
      v0.w = nb[p * 3 + 0];
      v1.x = nb[p * 3 + 1];
      v1.y = nb[p * 3 + 2];
      v1.z = fb[p];
      v1.w = fb[NN + p];
      v2.x = fb[2 * NN + p];
      v2.y = fb[3 * NN + p];
      v2.z = fb[4 * NN + p];
      v2.w = fb[5 * NN + p];
      float4* dst = (float4*)(x0 + (pos_base + (size_t)slot) * 12);
      dst[0] = v0; dst[1] = v1; dst[2] = v2;
    }
    total += (int)__popcll(msk);
  }
  if (total < SS) {                                // pad with first hit (ref semantics)
    if (first_p < 0) first_p = 0;
    const int p = first_p;
    const float ppx = cb[p * 3], ppy = cb[p * 3 + 1], ppz = cb[p * 3 + 2];
    float4 v0, v1, v2;
    v0.x = ppx - qx; v0.y = ppy - qy; v0.z = ppz - qz;
    v0.w = nb[p * 3 + 0]; v1.x = nb[p * 3 + 1]; v1.y = nb[p * 3 + 2];
    v1.z = fb[p]; v1.w = fb[NN + p];
    v2.x = fb[2 * NN + p]; v2.y = fb[3 * NN + p]; v2.z = fb[4 * NN + p]; v2.w = fb[5 * NN + p];
    for (int slot = total + lane; slot < SS; slot += 64) {
      float4* dst = (float4*)(x0 + (pos_base + (size_t)slot) * 12);
      dst[0] = v0; dst[1] = v1; dst[2] = v2;
    }
  }
}

// ==================================================================
// 3) stats for layer0 conv outputs (loc 64ch + ftr 64ch), lane = channel
// ==================================================================
__global__ __launch_bounds__(256) void stats0_kernel(
    const float* __restrict__ x0,
    const float* __restrict__ w_l0, const float* __restrict__ b_l0,
    const float* __restrict__ w_f0, const float* __restrict__ b_f0,
    float* __restrict__ stats) {
  const int lane = threadIdx.x & 63, wid = threadIdx.x >> 6;
  const int wgid = blockIdx.x * 4 + wid;           // 0..2047
  float wl[3], wf[9];
#pragma unroll
  for (int j = 0; j < 3; ++j) wl[j] = w_l0[lane * 3 + j];
#pragma unroll
  for (int j = 0; j < 9; ++j) wf[j] = w_f0[lane * 9 + j];
  const float bl = b_l0[lane], bf = b_f0[lane];
  float sL = 0.f, qL = 0.f, sF = 0.f, qF = 0.f;
  for (int it = 0; it < 128; ++it) {
    const int p = it * 2048 + wgid;
    const float4* row = (const float4*)(x0 + (size_t)p * 12);
    const float4 r0 = row[0], r1 = row[1], r2 = row[2];
    const float yL = bl + wl[0] * r0.x + wl[1] * r0.y + wl[2] * r0.z;
    const float yF = bf + wf[0] * r0.w + wf[1] * r1.x + wf[2] * r1.y + wf[3] * r1.z +
                     wf[4] * r1.w + wf[5] * r2.x + wf[6] * r2.y + wf[7] * r2.z + wf[8] * r2.w;
    sL += yL; qL += yL * yL; sF += yF; qF += yF * yF;
  }
  __shared__ float red[4][64][4];
  red[wid][lane][0] = sL; red[wid][lane][1] = qL;
  red[wid][lane][2] = sF; red[wid][lane][3] = qF;
  __syncthreads();
  if (wid == 0) {
    float a0 = 0.f, a1 = 0.f, a2 = 0.f, a3 = 0.f;
    for (int w = 0; w < 4; ++w) {
      a0 += red[w][lane][0]; a1 += red[w][lane][1];
      a2 += red[w][lane][2]; a3 += red[w][lane][3];
    }
    atomicAdd(&stats[ST_SUM0L + lane], a0);
    atomicAdd(&stats[ST_SQ0L + lane], a1);
    atomicAdd(&stats[ST_SUM0F + lane], a2);
    atomicAdd(&stats[ST_SQ0F + lane], a3);
  }
}

// ==================================================================
// finalize kernels: sums -> (a, b') with y_norm = a*y + b'
// ==================================================================
__global__ void finalize0_kernel(float* stats, const float* gl, const float* bel,
                                 const float* gf, const float* bef) {
  const int t = threadIdx.x;                        // 128
  const float invN = 1.0f / (float)PTOT;
  if (t < 64) {
    const float mean = stats[ST_SUM0L + t] * invN;
    const float var  = stats[ST_SQ0L + t] * invN - mean * mean;
    const float a = gl[t] / sqrtf(var + 1e-5f);
    stats[P_AL + t] = a;
    stats[P_BL + t] = bel[t] - a * mean;
  } else {
    const int c = t - 64;
    const float mean = stats[ST_SUM0F + c] * invN;
    const float var  = stats[ST_SQ0F + c] * invN - mean * mean;
    const float a = gf[c] / sqrtf(var + 1e-5f);
    stats[P_AF + c] = a;
    stats[P_BF + c] = bef[c] - a * mean;
  }
}
__global__ void finalize1_kernel(float* stats, const float* g, const float* be) {
  const int t = threadIdx.x;                        // 64
  const float invN = 1.0f / (float)PTOT;
  const float mean = stats[ST_SUM1 + t] * invN;
  const float var  = stats[ST_SQ1 + t] * invN - mean * mean;
  const float a = g[t] / sqrtf(var + 1e-5f);
  stats[P_A1 + t] = a;
  stats[P_B1 + t] = be[t] - a * mean;
}
__global__ void finalize2_kernel(float* stats, const float* g, const float* be) {
  const int t = threadIdx.x;                        // 128
  const float invN = 1.0f / (float)PTOT;
  const float mean = stats[ST_SUM2 + t] * invN;
  const float var  = stats[ST_SQ2 + t] * invN - mean * mean;
  const float a = g[t] / sqrtf(var + 1e-5f);
  stats[P_A2 + t] = a;
  stats[P_B2 + t] = be[t] - a * mean;
}

// ==================================================================
// 5) conv0 + BN0 + relu  ->  conv1 (z1 stored f32) + stats1
//    lane = output channel; per-position x1 broadcast via wave-private LDS
// ==================================================================
__global__ __launch_bounds__(256) void k5_kernel(
    const float* __restrict__ x0, float* __restrict__ z1,
    float* __restrict__ stats,
    const float* __restrict__ w_l0, const float* __restrict__ b_l0,
    const float* __restrict__ w_f0, const float* __restrict__ b_f0,
    const float* __restrict__ w1, const float* __restrict__ b1) {
  const int lane = threadIdx.x & 63, wid = threadIdx.x >> 6;
  const int wgid = blockIdx.x * 4 + wid;
  float wl[3], wf[9], w1r[64];
#pragma unroll
  for (int j = 0; j < 3; ++j) wl[j] = w_l0[lane * 3 + j];
#pragma unroll
  for (int j = 0; j < 9; ++j) wf[j] = w_f0[lane * 9 + j];
#pragma unroll
  for (int k = 0; k < 64; ++k) w1r[k] = w1[lane * 64 + k];
  const float bl = b_l0[lane], bf = b_f0[lane], b1v = b1[lane];
  const float aL = stats[P_AL + lane], bL = stats[P_BL + lane];
  const float aF = stats[P_AF + lane], bF = stats[P_BF + lane];
  float s1 = 0.f, q1 = 0.f;
  __shared__ __align__(16) float sx[2][4][64];
  for (int it = 0; it < 128; ++it) {
    const int p = it * 2048 + wgid;
    const float4* row = (const float4*)(x0 + (size_t)p * 12);
    const float4 r0 = row[0], r1 = row[1], r2 = row[2];
    const float yL = bl + wl[0] * r0.x + wl[1] * r0.y + wl[2] * r0.z;
    const float yF = bf + wf[0] * r0.w + wf[1] * r1.x + wf[2] * r1.y + wf[3] * r1.z +
                     wf[4] * r1.w + wf[5] * r2.x + wf[6] * r2.y + wf[7] * r2.z + wf[8] * r2.w;
    const float x1 = fmaxf(aL * yL + bL + (aF * yF + bF), 0.f);
    sx[it & 1][wid][lane] = x1;
    __syncthreads();
    float acc = b1v;
    const float4* xv = (const float4*)&sx[it & 1][wid][0];
#pragma unroll
    for (int k4 = 0; k4 < 16; ++k4) {
      const float4 xq = xv[k4];
      acc += w1r[4 * k4 + 0] * xq.x + w1r[4 * k4 + 1] * xq.y +
             w1r[4 * k4 + 2] * xq.z + w1r[4 * k4 + 3] * xq.w;
    }
    s1 += acc; q1 += acc * acc;
    z1[(size_t)p * 64 + lane] = acc;
  }
  __shared__ float red[4][64][2];
  red[wid][lane][0] = s1; red[wid][lane][1] = q1;
  __syncthreads();
  if (wid == 0) {
    float a0 = 0.f, a1v = 0.f;
    for (int w = 0; w < 4; ++w) { a0 += red[w][lane][0]; a1v += red[w][lane][1]; }
    atomicAdd(&stats[ST_SUM1 + lane], a0);
    atomicAdd(&stats[ST_SQ1 + lane], a1v);
  }
}

// ==================================================================
// 6) BN1+relu -> conv2 (128ch) + stats2; z2 written bf16 IN-PLACE over z1
// ==================================================================
__global__ __launch_bounds__(256, 2) void k6_kernel(
    float* __restrict__ z12, float* __restrict__ stats,
    const float* __restrict__ w2, const float* __restrict__ b2) {
  const int lane = threadIdx.x & 63, wid = threadIdx.x >> 6;
  const int wgid = blockIdx.x * 4 + wid;
  float w2a[64], w2b[64];
#pragma unroll
  for (int k = 0; k < 64; ++k) w2a[k] = w2[lane * 64 + k];
#pragma unroll
  for (int k = 0; k < 64; ++k) w2b[k] = w2[(lane + 64) * 64 + k];
  const float b2a = b2[lane], b2b = b2[lane + 64];
  const float a1 = stats[P_A1 + lane], b1p = stats[P_B1 + lane];
  float s0 = 0.f, q0 = 0.f, s1 = 0.f, q1 = 0.f;
  __shared__ __align__(16) float sx[2][4][64];
  __hip_bfloat16* zo = (__hip_bfloat16*)z12;
  for (int it = 0; it < 128; ++it) {
    const int p = it * 2048 + wgid;
    const float z = z12[(size_t)p * 64 + lane];
    const float x2 = fmaxf(a1 * z + b1p, 0.f);
    sx[it & 1][wid][lane] = x2;
    __syncthreads();
    float acc0 = b2a, acc1 = b2b;
    const float4* xv = (const float4*)&sx[it & 1][wid][0];
#pragma unroll
    for (int k4 = 0; k4 < 16; ++k4) {
      const float4 xq = xv[k4];
      acc0 += w2a[4 * k4] * xq.x + w2a[4 * k4 + 1] * xq.y + w2a[4 * k4 + 2] * xq.z + w2a[4 * k4 + 3] * xq.w;
      acc1 += w2b[4 * k4] * xq.x + w2b[4 * k4 + 1] * xq.y + w2b[4 * k4 + 2] * xq.z + w2b[4 * k4 + 3] * xq.w;
    }
    s0 += acc0; q0 += acc0 * acc0; s1 += acc1; q1 += acc1 * acc1;
    zo[(size_t)p * 128 + lane]      = __float2bfloat16(acc0);
    zo[(size_t)p * 128 + 64 + lane] = __float2bfloat16(acc1);
  }
  __shared__ float red[4][64][4];
  red[wid][lane][0] = s0; red[wid][lane][1] = q0;
  red[wid][lane][2] = s1; red[wid][lane][3] = q1;
  __syncthreads();
  if (wid == 0) {
    float t0 = 0.f, t1 = 0.f, t2 = 0.f, t3 = 0.f;
    for (int w = 0; w < 4; ++w) {
      t0 += red[w][lane][0]; t1 += red[w][lane][1];
      t2 += red[w][lane][2]; t3 += red[w][lane][3];
    }
    atomicAdd(&stats[ST_SUM2 + lane], t0);
    atomicAdd(&stats[ST_SQ2 + lane], t1);
    atomicAdd(&stats[ST_SUM2 + 64 + lane], t2);
    atomicAdd(&stats[ST_SQ2 + 64 + lane], t3);
  }
}

// ==================================================================
// 7) BN2 + relu + max over nsample, transposed write via LDS tile
//    block = (b, 64-m tile); out x shape (8,128,1024)
// ==================================================================
__global__ __launch_bounds__(256) void k7_kernel(const __hip_bfloat16* __restrict__ z2,
                                                 const float* __restrict__ stats,
                                                 float* __restrict__ out3) {
  const int b = blockIdx.x >> 4;
  const int mt = blockIdx.x & 15;
  const int t = threadIdx.x;
  const int o = t & 127, h = t >> 7;
  const float a = stats[P_A2 + o], bb = stats[P_B2 + o];
  __shared__ float tile[128][65];
  for (int j = 0; j < 32; ++j) {
    const int ml = h + 2 * j;
    const size_t rowbase = ((size_t)(b * 1024 + mt * 64 + ml)) * SS;
    float acc = -1e30f;
    for (int s = 0; s < SS; ++s) {
      const float v = __bfloat162float(z2[(rowbase + s) * 128 + o]);
      acc = fmaxf(acc, a * v + bb);
    }
    tile[o][ml] = fmaxf(acc, 0.f);                 // relu after max (monotone)
  }
  __syncthreads();
  const int r = t >> 1, c0 = (t & 1) * 32;
  float* dst = out3 + (size_t)b * 128 * 1024 + (size_t)r * 1024 + mt * 64 + c0;
  for (int j = 0; j < 32; ++j) dst[j] = tile[r][c0 + j];
}

// ==================================================================
extern "C" void kernel_launch(void* const* d_in, const int* in_sizes, int n_in,
                              void* d_out, int out_size, void* d_ws, size_t ws_size,
                              hipStream_t stream) {
  const float* center  = (const float*)d_in[0];
  const float* normal  = (const float*)d_in[1];
  const float* feature = (const float*)d_in[2];
  const float* w_l0 = (const float*)d_in[3];
  const float* b_l0 = (const float*)d_in[4];
  const float* g_l0 = (const float*)d_in[5];
  const float* be_l0 = (const float*)d_in[6];
  const float* w_f0 = (const float*)d_in[7];
  const float* b_f0 = (const float*)d_in[8];
  const float* g_f0 = (const float*)d_in[9];
  const float* be_f0 = (const float*)d_in[10];
  const float* w1 = (const float*)d_in[11];
  const float* b1 = (const float*)d_in[12];
  const float* g1 = (const float*)d_in[13];
  const float* be1 = (const float*)d_in[14];
  const float* w2 = (const float*)d_in[15];
  const float* b2 = (const float*)d_in[16];
  const float* g2 = (const float*)d_in[17];
  const float* be2 = (const float*)d_in[18];
  float* out = (float*)d_out;
  char* ws = (char*)d_ws;
  int*   fps_idx = (int*)(ws + OFF_FPS);
  float* stats   = (float*)(ws + OFF_STATS);
  float* x0      = (float*)(ws + OFF_X0);
  float* z1      = (float*)(ws + OFF_Z1);

  hipMemsetAsync(stats, 0, STATS_ZERO_BYTES, stream);
  hipLaunchKernelGGL(fps_kernel, dim3(8), dim3(512), 0, stream, center, fps_idx);
  hipLaunchKernelGGL(ball_gather_kernel, dim3(2048), dim3(256), 0, stream,
                     center, normal, feature, fps_idx, x0, out);
  hipLaunchKernelGGL(stats0_kernel, dim3(512), dim3(256), 0, stream,
                     x0, w_l0, b_l0, w_f0, b_f0, stats);
  hipLaunchKernelGGL(finalize0_kernel, dim3(1), dim3(128), 0, stream,
                     stats, g_l0, be_l0, g_f0, be_f0);
  hipLaunchKernelGGL(k5_kernel, dim3(512), dim3(256), 0, stream,
                     x0, z1, stats, w_l0, b_l0, w_f0, b_f0, w1, b1);
  hipLaunchKernelGGL(finalize1_kernel, dim3(1), dim3(64), 0, stream, stats, g1, be1);
  hipLaunchKernelGGL(k6_kernel, dim3(512), dim3(256), 0, stream, z1, stats, w2, b2);
  hipLaunchKernelGGL(finalize2_kernel, dim3(1), dim3(128), 0, stream, stats, g2, be2);
  hipLaunchKernelGGL(k7_kernel, dim3(128), dim3(256), 0, stream,
                     (const __hip_bfloat16*)z1, stats, out + 49152);
}

// Round 8
// 1303.597 us; speedup vs baseline: 1.0528x; 1.0528x over previous
//
#include <hip/hip_runtime.h>
#include <hip/hip_bf16.h>
#include <cstdint>
#include <cstddef>

// ---------------- problem constants ----------------
#define BB 8
#define NN 8192
#define MM 1024
#define SS 32
#define PTOT (BB*MM*SS)          // 262144
// threshold must match f32(0.2*0.2 computed in double) — NOT 0.2f*0.2f
__device__ __constant__ float kR2 = 0.039999999105930328f;

// ---------------- stats layout (float offsets in ws) ----------------
#define ST_SUM0L 0
#define ST_SQ0L  64
#define ST_SUM0F 128
#define ST_SQ0F  192
#define ST_SUM1  256
#define ST_SQ1   320
#define ST_SUM2  384
#define ST_SQ2   512
#define STATS_ZERO_BYTES (640*4)

// ws byte offsets
#define OFF_FPS   0u
#define OFF_STATS 32768u
#define OFF_X0    40960u
#define OFF_Z1    12623872u      // x0 ends at 40960 + 262144*48 = 12623872

typedef float v2f __attribute__((ext_vector_type(2)));
typedef unsigned long long ull;

// u64-key max over DPP (rocPRIM wave64 ctrl sequence, validated R3-R6).
// Both halves use identical ctrl/masks -> pair comes from the same lane;
// masked/out-of-bounds lanes keep own value (max(v,v)=v harmless).
#define DPP_KMAX(k, ctrl, rm, bm) {                                        \
  const unsigned _lo = (unsigned)(k), _hi = (unsigned)((k) >> 32);         \
  const unsigned _nl = (unsigned)__builtin_amdgcn_update_dpp(              \
      (int)_lo, (int)_lo, ctrl, rm, bm, false);                            \
  const unsigned _nh = (unsigned)__builtin_amdgcn_update_dpp(              \
      (int)_hi, (int)_hi, ctrl, rm, bm, false);                            \
  const ull _o = ((ull)_nh << 32) | _nl;                                   \
  k = (_o > (k)) ? _o : (k); }

// ==================================================================
// 1) FPS — R5 configuration verbatim (measured best: 895us).
//    256 threads (4 waves, 1 wave/SIMD), 32 pts/thread pinned in
//    registers (asm "+v": cannot be rematerialized). Argmax via u64
//    key = (f32bits(T)<<32) | ~idx: max key == max distance, lowest
//    index on ties (np.argmax semantics). R6 falsified the
//    2-waves/SIMD variant (954us): the serial chain is barrier-
//    synchronized, extra waves add DPP/reduce issue > latency hidden.
//    Distance op order (contract off) -> bit-identical d.
// ==================================================================
__global__ __launch_bounds__(256, 1) void fps_kernel(const float* __restrict__ center,
                                                     int* __restrict__ fps_idx) {
  const int b = blockIdx.x;
  const int t = threadIdx.x;               // 0..255
  const int lane = t & 63, wid = t >> 6;   // 4 waves
  const float* cb = center + (size_t)b * NN * 3;
  __shared__ __align__(16) float4 sc[NN];            // 128 KB centroid table
  __shared__ ull s_wkey[2][4];
  v2f X[16], Y[16], Z[16], T[16];
  unsigned nidx[32];
#pragma unroll
  for (int j = 0; j < 16; ++j) {
    const int p0 = ((2 * j) << 8) | t;
    const int p1 = ((2 * j + 1) << 8) | t;
    const float x0 = cb[p0 * 3 + 0], y0 = cb[p0 * 3 + 1], z0 = cb[p0 * 3 + 2];
    const float x1 = cb[p1 * 3 + 0], y1 = cb[p1 * 3 + 1], z1 = cb[p1 * 3 + 2];
    sc[p0] = make_float4(x0, y0, z0, 0.f);
    sc[p1] = make_float4(x1, y1, z1, 0.f);
    X[j] = (v2f){x0, x1}; Y[j] = (v2f){y0, y1}; Z[j] = (v2f){z0, z1};
    T[j] = (v2f){1e10f, 1e10f};
    // pin: asm-defined values cannot be rematerialized from memory
    asm volatile("" : "+v"(X[j]), "+v"(Y[j]), "+v"(Z[j]));
  }
#pragma unroll
  for (int k = 0; k < 32; ++k) nidx[k] = ~(unsigned)((k << 8) | t);
  __syncthreads();
  int far = 0;
  for (int i = 0; i < MM; ++i) {
    if (t == 0) fps_idx[(b << 10) + i] = far;
    // centroid: uniform-address LDS broadcast read
    const float4 c = sc[__builtin_amdgcn_readfirstlane(far)];
    const v2f cx2 = (v2f){c.x, c.x};
    const v2f cy2 = (v2f){c.y, c.y};
    const v2f cz2 = (v2f){c.z, c.z};
    {
#pragma clang fp contract(off)
#pragma unroll
      for (int j = 0; j < 16; ++j) {
        const v2f dx = X[j] - cx2;
        const v2f dy = Y[j] - cy2;
        const v2f dz = Z[j] - cz2;
        v2f d = dx * dx;
        d = d + dy * dy;
        d = d + dz * dz;
        T[j] = __builtin_elementwise_min(T[j], d);
      }
    }
    // ---- per-thread u64 key tree (max dist, lowest idx on ties) ----
    ull K[16];
#pragma unroll
    for (int j = 0; j < 16; ++j) {
      const unsigned hx = __float_as_uint(T[j].x);
      const unsigned hy = __float_as_uint(T[j].y);
      const bool ygt = hy > hx;            // tie -> keep x (lower idx)
      const unsigned h = ygt ? hy : hx;
      const unsigned l = ygt ? nidx[2 * j + 1] : nidx[2 * j];
      K[j] = ((ull)h << 32) | l;
    }
#pragma unroll
    for (int s = 8; s >= 1; s >>= 1) {
#pragma unroll
      for (int j = 0; j < s; ++j) {
        const ull o = K[j + s];
        if (o > K[j]) K[j] = o;
      }
    }
    ull key = K[0];
    // ---- wave u64 max via DPP (lane 63 ends with the full reduce) ----
    DPP_KMAX(key, 0x111, 0xf, 0xf)
    DPP_KMAX(key, 0x112, 0xf, 0xf)
    DPP_KMAX(key, 0x114, 0xf, 0xe)
    DPP_KMAX(key, 0x118, 0xf, 0xc)
    DPP_KMAX(key, 0x142, 0xa, 0xf)
    DPP_KMAX(key, 0x143, 0xc, 0xf)
    if (lane == 63) s_wkey[i & 1][wid] = key;
    __syncthreads();
    const ull* sk = s_wkey[i & 1];
    const ull k0 = sk[0], k1 = sk[1], k2 = sk[2], k3 = sk[3];
    const ull h0 = (k1 > k0) ? k1 : k0;
    const ull h1 = (k3 > k2) ? k3 : k2;
    const ull best = (h1 > h0) ? h1 : h0;
    far = (int)(~(unsigned)best);
  }
}

// ==================================================================
// 2) Ball query (first 32 smallest in-radius indices) + gather + concat
//    one wave per (b,m); also writes new_center/new_normal outputs
// ==================================================================
__global__ __launch_bounds__(256) void ball_gather_kernel(
    const float* __restrict__ center, const float* __restrict__ normal,
    const float* __restrict__ feature, const int* __restrict__ fps_idx,
    float* __restrict__ x0, float* __restrict__ out) {
  const int lane = threadIdx.x & 63;
  const int wq = (int)((blockIdx.x * blockDim.x + threadIdx.x) >> 6); // 0..8191
  const int b = wq >> 10, m = wq & 1023;
  const float* cb = center  + (size_t)b * NN * 3;
  const float* nb = normal  + (size_t)b * NN * 3;
  const float* fb = feature + (size_t)b * 6 * NN;
  const int pstar = fps_idx[(b << 10) + m];
  const float qx = cb[pstar * 3 + 0], qy = cb[pstar * 3 + 1], qz = cb[pstar * 3 + 2];
  if (lane < 3) {
    out[b * 3072 + lane * 1024 + m]         = cb[pstar * 3 + lane];   // new_center^T
    out[24576 + b * 3072 + lane * 1024 + m] = nb[pstar * 3 + lane];   // new_normal^T
  }
  const size_t pos_base = (size_t)((b << 10) + m) * SS;
  int total = 0;
  int first_p = -1;
  const float r2 = kR2;
  for (int base = 0; base < NN && total < SS; base += 64) {
    const int p = base + lane;
    const float ppx = cb[p * 3], ppy = cb[p * 3 + 1], ppz = cb[p * 3 + 2];
    const float dx = ppx - qx, dy = ppy - qy, dz = ppz - qz;
    float d2;
    {
#pragma clang fp contract(off)
      d2 = dx * dx;
      d2 = d2 + dy * dy;
      d2 = d2 + dz * dz;
    }
    const bool hit = d2 < r2;
    const unsigned long long msk = __ballot(hit);
    if (first_p < 0 && msk) first_p = base + (int)__builtin_ctzll(msk);
    const int rank = (int)__popcll(msk & ((1ull << lane) - 1ull));
    const int slot = total + rank;
    if (hit && slot < SS) {
      float4 v0, v1, v2;
      v0.x = dx; v0.y = dy; v0.z = dz;             // group_center - new_center
      v0.w = nb[p * 3 + 0];
      v1.x = nb[p * 3 + 1];
      v1.y = nb[p * 3 + 2];
      v1.z = fb[p];
      v1.w = fb[NN + p];
      v2.x = fb[2 * NN + p];
      v2.y = fb[3 * NN + p];
      v2.z = fb[4 * NN + p];
      v2.w = fb[5 * NN + p];
      float4* dst = (float4*)(x0 + (pos_base + (size_t)slot) * 12);
      dst[0] = v0; dst[1] = v1; dst[2] = v2;
    }
    total += (int)__popcll(msk);
  }
  if (total < SS) {                                // pad with first hit (ref semantics)
    if (first_p < 0) first_p = 0;
    const int p = first_p;
    const float ppx = cb[p * 3], ppy = cb[p * 3 + 1], ppz = cb[p * 3 + 2];
    float4 v0, v1, v2;
    v0.x = ppx - qx; v0.y = ppy - qy; v0.z = ppz - qz;
    v0.w = nb[p * 3 + 0]; v1.x = nb[p * 3 + 1]; v1.y = nb[p * 3 + 2];
    v1.z = fb[p]; v1.w = fb[NN + p];
    v2.x = fb[2 * NN + p]; v2.y = fb[3 * NN + p]; v2.z = fb[4 * NN + p]; v2.w = fb[5 * NN + p];
    for (int slot = total + lane; slot < SS; slot += 64) {
      float4* dst = (float4*)(x0 + (pos_base + (size_t)slot) * 12);
      dst[0] = v0; dst[1] = v1; dst[2] = v2;
    }
  }
}

// ==================================================================
// 3) stats for layer0 conv outputs (loc 64ch + ftr 64ch), lane = channel
// ==================================================================
__global__ __launch_bounds__(256) void stats0_kernel(
    const float* __restrict__ x0,
    const float* __restrict__ w_l0, const float* __restrict__ b_l0,
    const float* __restrict__ w_f0, const float* __restrict__ b_f0,
    float* __restrict__ stats) {
  const int lane = threadIdx.x & 63, wid = threadIdx.x >> 6;
  const int wgid = blockIdx.x * 4 + wid;           // 0..2047
  float wl[3], wf[9];
#pragma unroll
  for (int j = 0; j < 3; ++j) wl[j] = w_l0[lane * 3 + j];
#pragma unroll
  for (int j = 0; j < 9; ++j) wf[j] = w_f0[lane * 9 + j];
  const float bl = b_l0[lane], bf = b_f0[lane];
  float sL = 0.f, qL = 0.f, sF = 0.f, qF = 0.f;
  for (int it = 0; it < 128; ++it) {
    const int p = it * 2048 + wgid;
    const float4* row = (const float4*)(x0 + (size_t)p * 12);
    const float4 r0 = row[0], r1 = row[1], r2 = row[2];
    const float yL = bl + wl[0] * r0.x + wl[1] * r0.y + wl[2] * r0.z;
    const float yF = bf + wf[0] * r0.w + wf[1] * r1.x + wf[2] * r1.y + wf[3] * r1.z +
                     wf[4] * r1.w + wf[5] * r2.x + wf[6] * r2.y + wf[7] * r2.z + wf[8] * r2.w;
    sL += yL; qL += yL * yL; sF += yF; qF += yF * yF;
  }
  __shared__ float red[4][64][4];
  red[wid][lane][0] = sL; red[wid][lane][1] = qL;
  red[wid][lane][2] = sF; red[wid][lane][3] = qF;
  __syncthreads();
  if (wid == 0) {
    float a0 = 0.f, a1 = 0.f, a2 = 0.f, a3 = 0.f;
    for (int w = 0; w < 4; ++w) {
      a0 += red[w][lane][0]; a1 += red[w][lane][1];
      a2 += red[w][lane][2]; a3 += red[w][lane][3];
    }
    atomicAdd(&stats[ST_SUM0L + lane], a0);
    atomicAdd(&stats[ST_SQ0L + lane], a1);
    atomicAdd(&stats[ST_SUM0F + lane], a2);
    atomicAdd(&stats[ST_SQ0F + lane], a3);
  }
}

// ==================================================================
// 5) conv0 + BN0 + relu  ->  conv1 (z1 stored f32) + stats1
//    BN0 params computed in-prologue from raw sums (finalize0 folded;
//    the k5 launch boundary already guarantees stats0 completion; the
//    float expression sequence matches the old finalize0 exactly ->
//    bit-identical a,b').
// ==================================================================
__global__ __launch_bounds__(256) void k5_kernel(
    const float* __restrict__ x0, float* __restrict__ z1,
    float* __restrict__ stats,
    const float* __restrict__ w_l0, const float* __restrict__ b_l0,
    const float* __restrict__ w_f0, const float* __restrict__ b_f0,
    const float* __restrict__ gl, const float* __restrict__ bel,
    const float* __restrict__ gf, const float* __restrict__ bef,
    const float* __restrict__ w1, const float* __restrict__ b1) {
  const int lane = threadIdx.x & 63, wid = threadIdx.x >> 6;
  const int wgid = blockIdx.x * 4 + wid;
  float wl[3], wf[9], w1r[64];
#pragma unroll
  for (int j = 0; j < 3; ++j) wl[j] = w_l0[lane * 3 + j];
#pragma unroll
  for (int j = 0; j < 9; ++j) wf[j] = w_f0[lane * 9 + j];
#pragma unroll
  for (int k = 0; k < 64; ++k) w1r[k] = w1[lane * 64 + k];
  const float bl = b_l0[lane], bf = b_f0[lane], b1v = b1[lane];
  const float invN = 1.0f / (float)PTOT;
  // finalize0 (folded): identical op sequence
  const float meanL = stats[ST_SUM0L + lane] * invN;
  const float varL  = stats[ST_SQ0L + lane] * invN - meanL * meanL;
  const float aL = gl[lane] / sqrtf(varL + 1e-5f);
  const float bL = bel[lane] - aL * meanL;
  const float meanF = stats[ST_SUM0F + lane] * invN;
  const float varF  = stats[ST_SQ0F + lane] * invN - meanF * meanF;
  const float aF = gf[lane] / sqrtf(varF + 1e-5f);
  const float bF = bef[lane] - aF * meanF;
  float s1 = 0.f, q1 = 0.f;
  __shared__ __align__(16) float sx[2][4][64];
  for (int it = 0; it < 128; ++it) {
    const int p = it * 2048 + wgid;
    const float4* row = (const float4*)(x0 + (size_t)p * 12);
    const float4 r0 = row[0], r1 = row[1], r2 = row[2];
    const float yL = bl + wl[0] * r0.x + wl[1] * r0.y + wl[2] * r0.z;
    const float yF = bf + wf[0] * r0.w + wf[1] * r1.x + wf[2] * r1.y + wf[3] * r1.z +
                     wf[4] * r1.w + wf[5] * r2.x + wf[6] * r2.y + wf[7] * r2.z + wf[8] * r2.w;
    const float x1 = fmaxf(aL * yL + bL + (aF * yF + bF), 0.f);
    sx[it & 1][wid][lane] = x1;
    __syncthreads();
    float acc = b1v;
    const float4* xv = (const float4*)&sx[it & 1][wid][0];
#pragma unroll
    for (int k4 = 0; k4 < 16; ++k4) {
      const float4 xq = xv[k4];
      acc += w1r[4 * k4 + 0] * xq.x + w1r[4 * k4 + 1] * xq.y +
             w1r[4 * k4 + 2] * xq.z + w1r[4 * k4 + 3] * xq.w;
    }
    s1 += acc; q1 += acc * acc;
    z1[(size_t)p * 64 + lane] = acc;
  }
  __shared__ float red[4][64][2];
  red[wid][lane][0] = s1; red[wid][lane][1] = q1;
  __syncthreads();
  if (wid == 0) {
    float a0 = 0.f, a1v = 0.f;
    for (int w = 0; w < 4; ++w) { a0 += red[w][lane][0]; a1v += red[w][lane][1]; }
    atomicAdd(&stats[ST_SUM1 + lane], a0);
    atomicAdd(&stats[ST_SQ1 + lane], a1v);
  }
}

// ==================================================================
// 6) BN1+relu -> conv2 (128ch) + stats2; z2 written bf16 IN-PLACE over z1
//    BN1 params computed in-prologue from raw sums (finalize1 folded)
// ==================================================================
__global__ __launch_bounds__(256, 2) void k6_kernel(
    float* __restrict__ z12, float* __restrict__ stats,
    const float* __restrict__ g1, const float* __restrict__ be1,
    const float* __restrict__ w2, const float* __restrict__ b2) {
  const int lane = threadIdx.x & 63, wid = threadIdx.x >> 6;
  const int wgid = blockIdx.x * 4 + wid;
  float w2a[64], w2b[64];
#pragma unroll
  for (int k = 0; k < 64; ++k) w2a[k] = w2[lane * 64 + k];
#pragma unroll
  for (int k = 0; k < 64; ++k) w2b[k] = w2[(lane + 64) * 64 + k];
  const float b2a = b2[lane], b2b = b2[lane + 64];
  const float invN = 1.0f / (float)PTOT;
  // finalize1 (folded): identical op sequence
  const float mean1 = stats[ST_SUM1 + lane] * invN;
  const float var1  = stats[ST_SQ1 + lane] * invN - mean1 * mean1;
  const float a1 = g1[lane] / sqrtf(var1 + 1e-5f);
  const float b1p = be1[lane] - a1 * mean1;
  float s0 = 0.f, q0 = 0.f, s1 = 0.f, q1 = 0.f;
  __shared__ __align__(16) float sx[2][4][64];
  __hip_bfloat16* zo = (__hip_bfloat16*)z12;
  for (int it = 0; it < 128; ++it) {
    const int p = it * 2048 + wgid;
    const float z = z12[(size_t)p * 64 + lane];
    const float x2 = fmaxf(a1 * z + b1p, 0.f);
    sx[it & 1][wid][lane] = x2;
    __syncthreads();
    float acc0 = b2a, acc1 = b2b;
    const float4* xv = (const float4*)&sx[it & 1][wid][0];
#pragma unroll
    for (int k4 = 0; k4 < 16; ++k4) {
      const float4 xq = xv[k4];
      acc0 += w2a[4 * k4] * xq.x + w2a[4 * k4 + 1] * xq.y + w2a[4 * k4 + 2] * xq.z + w2a[4 * k4 + 3] * xq.w;
      acc1 += w2b[4 * k4] * xq.x + w2b[4 * k4 + 1] * xq.y + w2b[4 * k4 + 2] * xq.z + w2b[4 * k4 + 3] * xq.w;
    }
    s0 += acc0; q0 += acc0 * acc0; s1 += acc1; q1 += acc1 * acc1;
    zo[(size_t)p * 128 + lane]      = __float2bfloat16(acc0);
    zo[(size_t)p * 128 + 64 + lane] = __float2bfloat16(acc1);
  }
  __shared__ float red[4][64][4];
  red[wid][lane][0] = s0; red[wid][lane][1] = q0;
  red[wid][lane][2] = s1; red[wid][lane][3] = q1;
  __syncthreads();
  if (wid == 0) {
    float t0 = 0.f, t1 = 0.f, t2 = 0.f, t3 = 0.f;
    for (int w = 0; w < 4; ++w) {
      t0 += red[w][lane][0]; t1 += red[w][lane][1];
      t2 += red[w][lane][2]; t3 += red[w][lane][3];
    }
    atomicAdd(&stats[ST_SUM2 + lane], t0);
    atomicAdd(&stats[ST_SQ2 + lane], t1);
    atomicAdd(&stats[ST_SUM2 + 64 + lane], t2);
    atomicAdd(&stats[ST_SQ2 + 64 + lane], t3);
  }
}

// ==================================================================
// 7) BN2 + relu + max over nsample, transposed write via LDS tile
//    BN2 params computed in-prologue from raw sums (finalize2 folded)
// ==================================================================
__global__ __launch_bounds__(256) void k7_kernel(const __hip_bfloat16* __restrict__ z2,
                                                 const float* __restrict__ stats,
                                                 const float* __restrict__ g2,
                                                 const float* __restrict__ be2,
                                                 float* __restrict__ out3) {
  const int b = blockIdx.x >> 4;
  const int mt = blockIdx.x & 15;
  const int t = threadIdx.x;
  const int o = t & 127, h = t >> 7;
  const float invN = 1.0f / (float)PTOT;
  // finalize2 (folded): identical op sequence
  const float mean2 = stats[ST_SUM2 + o] * invN;
  const float var2  = stats[ST_SQ2 + o] * invN - mean2 * mean2;
  const float a = g2[o] / sqrtf(var2 + 1e-5f);
  const float bb = be2[o] - a * mean2;
  __shared__ float tile[128][65];
  for (int j = 0; j < 32; ++j) {
    const int ml = h + 2 * j;
    const size_t rowbase = ((size_t)(b * 1024 + mt * 64 + ml)) * SS;
    float acc = -1e30f;
    for (int s = 0; s < SS; ++s) {
      const float v = __bfloat162float(z2[(rowbase + s) * 128 + o]);
      acc = fmaxf(acc, a * v + bb);
    }
    tile[o][ml] = fmaxf(acc, 0.f);                 // relu after max (monotone)
  }
  __syncthreads();
  const int r = t >> 1, c0 = (t & 1) * 32;
  float* dst = out3 + (size_t)b * 128 * 1024 + (size_t)r * 1024 + mt * 64 + c0;
  for (int j = 0; j < 32; ++j) dst[j] = tile[r][c0 + j];
}

// ==================================================================
extern "C" void kernel_launch(void* const* d_in, const int* in_sizes, int n_in,
                              void* d_out, int out_size, void* d_ws, size_t ws_size,
                              hipStream_t stream) {
  const float* center  = (const float*)d_in[0];
  const float* normal  = (const float*)d_in[1];
  const float* feature = (const float*)d_in[2];
  const float* w_l0 = (const float*)d_in[3];
  const float* b_l0 = (const float*)d_in[4];
  const float* g_l0 = (const float*)d_in[5];
  const float* be_l0 = (const float*)d_in[6];
  const float* w_f0 = (const float*)d_in[7];
  const float* b_f0 = (const float*)d_in[8];
  const float* g_f0 = (const float*)d_in[9];
  const float* be_f0 = (const float*)d_in[10];
  const float* w1 = (const float*)d_in[11];
  const float* b1 = (const float*)d_in[12];
  const float* g1 = (const float*)d_in[13];
  const float* be1 = (const float*)d_in[14];
  const float* w2 = (const float*)d_in[15];
  const float* b2 = (const float*)d_in[16];
  const float* g2 = (const float*)d_in[17];
  const float* be2 = (const float*)d_in[18];
  float* out = (float*)d_out;
  char* ws = (char*)d_ws;
  int*   fps_idx = (int*)(ws + OFF_FPS);
  float* stats   = (float*)(ws + OFF_STATS);
  float* x0      = (float*)(ws + OFF_X0);
  float* z1      = (float*)(ws + OFF_Z1);

  hipMemsetAsync(stats, 0, STATS_ZERO_BYTES, stream);
  hipLaunchKernelGGL(fps_kernel, dim3(8), dim3(256), 0, stream, center, fps_idx);
  hipLaunchKernelGGL(ball_gather_kernel, dim3(2048), dim3(256), 0, stream,
                     center, normal, feature, fps_idx, x0, out);
  hipLaunchKernelGGL(stats0_kernel, dim3(512), dim3(256), 0, stream,
                     x0, w_l0, b_l0, w_f0, b_f0, stats);
  hipLaunchKernelGGL(k5_kernel, dim3(512), dim3(256), 0, stream,
                     x0, z1, stats, w_l0, b_l0, w_f0, b_f0,
                     g_l0, be_l0, g_f0, be_f0, w1, b1);
  hipLaunchKernelGGL(k6_kernel, dim3(512), dim3(256), 0, stream,
                     z1, stats, g1, be1, w2, b2);
  hipLaunchKernelGGL(k7_kernel, dim3(128), dim3(256), 0, stream,
                     (const __hip_bfloat16*)z1, stats, g2, be2, out + 49152);
}